// Round 1
// baseline (355.833 us; speedup 1.0000x reference)
//
#include <hip/hip_runtime.h>

// Problem constants (B, LIN, E, D, N) = (32, 2048, 512, 512, 2)
#define B_SZ 32
#define L_SZ 2048
#define E_SZ 512
#define D_SZ 512
#define ND   1024   // N*D
// ws layout: dec_proj (32*512 f32) | Bt (512*512 bf16, [n][k]) | scores (32*2048 f32)
#define WS_DEC_OFF 0
#define WS_BT_OFF  (32*512*4)
#define WS_SC_OFF  (32*512*4 + 512*512*2)

typedef unsigned short ushort_t;
typedef unsigned int   uint_t;
typedef __attribute__((ext_vector_type(8))) short short8;   // 8 bf16 = 4 VGPRs (MFMA A/B frag)
typedef __attribute__((ext_vector_type(4))) float floatx4;  // MFMA C/D frag

// exact RNE float->bf16 (inputs are finite randoms; no NaN care needed)
__device__ __forceinline__ ushort_t f2bf(float f) {
  uint_t u = __builtin_bit_cast(uint_t, f);
  u += 0x7fffu + ((u >> 16) & 1u);
  return (ushort_t)(u >> 16);
}

__device__ __forceinline__ float fast_tanh(float x) {
  // tanh(x) = 1 - 2/(exp(2x)+1); v_exp + v_rcp, ~1e-6 rel err, plenty for 2% threshold
  float e = __expf(2.0f * x);
  return 1.0f - 2.0f * __builtin_amdgcn_rcpf(e + 1.0f);
}

// ---------------------------------------------------------------------------
// Prep: blocks 0..31  -> dec_proj[b][d] = d_flat[b] @ W1[:1024] + b1   (fp32)
//       blocks 32..95 -> Bt[n][k] = bf16(W1[1024+k][n])  (transposed, k-contig)
// ---------------------------------------------------------------------------
__global__ __launch_bounds__(256) void prep_k(const float* __restrict__ dh,
                                              const float* __restrict__ W1,
                                              const float* __restrict__ b1,
                                              float* __restrict__ dec,
                                              ushort_t* __restrict__ Bt) {
  int blk = blockIdx.x;
  int t = threadIdx.x;
  if (blk < 32) {
    int b = blk;
    __shared__ float sd[ND];
    #pragma unroll
    for (int i = 0; i < 4; i++) sd[t + i * 256] = dh[b * ND + t + i * 256];
    __syncthreads();
    float a0 = 0.f, a1 = 0.f;
    #pragma unroll 8
    for (int k = 0; k < ND; k++) {
      float dv = sd[k];
      a0 = fmaf(dv, W1[k * D_SZ + t], a0);
      a1 = fmaf(dv, W1[k * D_SZ + t + 256], a1);
    }
    dec[b * D_SZ + t]       = a0 + b1[t];
    dec[b * D_SZ + t + 256] = a1 + b1[t + 256];
  } else {
    // 64x64 transpose tiles over W1_e (rows 1024..1535 of W1)
    int tt = blk - 32;
    int tk = (tt >> 3) * 64, tn = (tt & 7) * 64;
    __shared__ float tile[64][65];
    int c = t & 63, r0 = t >> 6;
    #pragma unroll
    for (int i = 0; i < 16; i++) {
      int r = r0 + i * 4;
      tile[r][c] = W1[(ND + tk + r) * D_SZ + tn + c];
    }
    __syncthreads();
    #pragma unroll
    for (int i = 0; i < 16; i++) {
      int n = r0 + i * 4;
      Bt[(tn + n) * E_SZ + tk + c] = f2bf(tile[c][n]);
    }
  }
}

// ---------------------------------------------------------------------------
// Main: one WG = 64 rows (one b, l-tile) x ALL 512 cols, K=512 in BK=64 windows.
// A (enc) read from HBM exactly once. enc_proj never materialized: epilogue does
// +dec_proj, tanh, *w2, row-reduce -> scores.
// 4 waves: wave w owns cols [w*128, w*128+128) (4 mt x 8 nt tiles of 16x16x32).
// LDS tiles XOR-swizzled in 16B chunks: chunk c of row r stored at pos c^(r&7)
// -> conflict-free ds_read_b128 fragments, rows stay contiguous (128B).
// ---------------------------------------------------------------------------
__global__ __launch_bounds__(256, 2) void main_k(const float* __restrict__ enc,
                                                 const ushort_t* __restrict__ Bt,
                                                 const float* __restrict__ dec,
                                                 const float* __restrict__ w2,
                                                 float* __restrict__ scores) {
  const int b  = blockIdx.y;
  const int l0 = blockIdx.x * 64;
  const int t  = threadIdx.x;
  const int wave = t >> 6, lane = t & 63;
  const int col = lane & 15, quad = lane >> 4;

  __shared__ ushort_t As[64 * 64];    // 8 KB  [m][k] bf16, swizzled
  __shared__ ushort_t Bs[512 * 64];   // 64 KB [n][k] bf16, swizzled
  __shared__ float s_sc[64];

  if (t < 64) s_sc[t] = 0.f;

  floatx4 acc[4][8];
  #pragma unroll
  for (int mt = 0; mt < 4; mt++)
    #pragma unroll
    for (int nt = 0; nt < 8; nt++)
      acc[mt][nt] = (floatx4){0.f, 0.f, 0.f, 0.f};

  const float* arow = enc + (size_t)(b * L_SZ + l0) * E_SZ;

  for (int kw = 0; kw < 8; kw++) {
    const int k0 = kw * 64;
    __syncthreads();  // protect LDS reuse from previous window's readers
    // ---- stage A: 512 chunks of 16B (8 bf16), 2 per thread, fp32->bf16 ----
    #pragma unroll
    for (int i = 0; i < 2; i++) {
      int cid = i * 256 + t;
      int m = cid >> 3, c = cid & 7;
      const float* gp = arow + m * E_SZ + k0 + c * 8;
      float4 f0 = *(const float4*)gp;
      float4 f1 = *(const float4*)(gp + 4);
      union { short8 v; ushort_t u[8]; } pk;
      pk.u[0] = f2bf(f0.x); pk.u[1] = f2bf(f0.y); pk.u[2] = f2bf(f0.z); pk.u[3] = f2bf(f0.w);
      pk.u[4] = f2bf(f1.x); pk.u[5] = f2bf(f1.y); pk.u[6] = f2bf(f1.z); pk.u[7] = f2bf(f1.w);
      *(short8*)&As[m * 64 + ((c ^ (m & 7)) << 3)] = pk.v;
    }
    // ---- stage B: 4096 chunks of 16B, 16 per thread (already bf16, L2-hot) ----
    #pragma unroll
    for (int i = 0; i < 16; i++) {
      int cid = i * 256 + t;
      int n = cid >> 3, c = cid & 7;
      uint4 v = *(const uint4*)(Bt + n * E_SZ + k0 + c * 8);
      *(uint4*)&Bs[n * 64 + ((c ^ (n & 7)) << 3)] = v;
    }
    __syncthreads();
    // ---- MFMA: 2 k-steps of 32, per wave 4x8 tiles ----
    #pragma unroll
    for (int ks = 0; ks < 2; ks++) {
      short8 af[4], bfr[8];
      #pragma unroll
      for (int mt = 0; mt < 4; mt++) {
        int m = mt * 16 + col;  // A frag: lane holds A[m=lane&15][k=quad*8+j]
        af[mt] = *(const short8*)&As[m * 64 + ((((ks << 2) + quad) ^ (m & 7)) << 3)];
      }
      #pragma unroll
      for (int nt = 0; nt < 8; nt++) {
        int n = wave * 128 + nt * 16 + col;  // B frag: lane holds B[k=quad*8+j][n=lane&15]
        bfr[nt] = *(const short8*)&Bs[n * 64 + ((((ks << 2) + quad) ^ (n & 7)) << 3)];
      }
      #pragma unroll
      for (int mt = 0; mt < 4; mt++)
        #pragma unroll
        for (int nt = 0; nt < 8; nt++)
          acc[mt][nt] = __builtin_amdgcn_mfma_f32_16x16x32_bf16(af[mt], bfr[nt], acc[mt][nt], 0, 0, 0);
    }
  }

  // ---- epilogue: x = acc + dec_proj; scores += tanh(x)*w2, reduced over n ----
  // C/D layout: D[row=quad*4+r][col=lane&15]  => m = mt*16+quad*4+r, n = wave*128+nt*16+col
  const float* decb = dec + b * D_SZ;
  float sums[4][4];
  #pragma unroll
  for (int mt = 0; mt < 4; mt++)
    #pragma unroll
    for (int r = 0; r < 4; r++) sums[mt][r] = 0.f;

  #pragma unroll
  for (int nt = 0; nt < 8; nt++) {
    int n = wave * 128 + nt * 16 + col;
    float dv = decb[n];
    float wv = w2[n];
    #pragma unroll
    for (int mt = 0; mt < 4; mt++)
      #pragma unroll
      for (int r = 0; r < 4; r++)
        sums[mt][r] += fast_tanh(acc[mt][nt][r] + dv) * wv;
  }
  #pragma unroll
  for (int mt = 0; mt < 4; mt++) {
    #pragma unroll
    for (int r = 0; r < 4; r++) {
      float v = sums[mt][r];
      v += __shfl_xor(v, 1, 16);
      v += __shfl_xor(v, 2, 16);
      v += __shfl_xor(v, 4, 16);
      v += __shfl_xor(v, 8, 16);
      if (col == 0) atomicAdd(&s_sc[mt * 16 + quad * 4 + r], v);  // 4 waves/row
    }
  }
  __syncthreads();
  if (t < 64) scores[b * L_SZ + l0 + t] = s_sc[t];
}

// ---------------------------------------------------------------------------
// Softmax over each row of 2048 scores. One WG per b.
// ---------------------------------------------------------------------------
__global__ __launch_bounds__(256) void softmax_k(const float* __restrict__ sc,
                                                 float* __restrict__ out) {
  int b = blockIdx.x, t = threadIdx.x;
  int wave = t >> 6, lane = t & 63;
  __shared__ float red[8];
  const float* row = sc + b * L_SZ;
  float v[8];
  float mx = -1e30f;
  #pragma unroll
  for (int i = 0; i < 8; i++) { v[i] = row[t + i * 256]; mx = fmaxf(mx, v[i]); }
  #pragma unroll
  for (int off = 32; off >= 1; off >>= 1) mx = fmaxf(mx, __shfl_xor(mx, off, 64));
  if (lane == 0) red[wave] = mx;
  __syncthreads();
  mx = fmaxf(fmaxf(red[0], red[1]), fmaxf(red[2], red[3]));
  float s = 0.f;
  #pragma unroll
  for (int i = 0; i < 8; i++) { v[i] = __expf(v[i] - mx); s += v[i]; }
  #pragma unroll
  for (int off = 32; off >= 1; off >>= 1) s += __shfl_xor(s, off, 64);
  if (lane == 0) red[4 + wave] = s;
  __syncthreads();
  s = red[4] + red[5] + red[6] + red[7];
  float inv = 1.0f / s;
  #pragma unroll
  for (int i = 0; i < 8; i++) out[b * L_SZ + t + i * 256] = v[i] * inv;
}

extern "C" void kernel_launch(void* const* d_in, const int* in_sizes, int n_in,
                              void* d_out, int out_size, void* d_ws, size_t ws_size,
                              hipStream_t stream) {
  const float* d_hidden = (const float*)d_in[0];   // (32, 2, 512)
  const float* enc      = (const float*)d_in[1];   // (32, 2048, 512)
  const float* W1       = (const float*)d_in[2];   // (1536, 512)
  const float* b1       = (const float*)d_in[3];   // (512,)
  const float* w2       = (const float*)d_in[4];   // (512,)
  float* out = (float*)d_out;                      // (32, 2048)

  char* ws = (char*)d_ws;
  float*    dec = (float*)(ws + WS_DEC_OFF);
  ushort_t* Bt  = (ushort_t*)(ws + WS_BT_OFF);
  float*    sc  = (float*)(ws + WS_SC_OFF);

  prep_k<<<96, 256, 0, stream>>>(d_hidden, W1, b1, dec, Bt);
  main_k<<<dim3(32, 32), 256, 0, stream>>>(enc, Bt, dec, w2, sc);
  softmax_k<<<32, 256, 0, stream>>>(sc, out);
}

// Round 2
// 237.137 us; speedup vs baseline: 1.5005x; 1.5005x over previous
//
#include <hip/hip_runtime.h>
#include <hip/hip_bf16.h>

// (B, LIN, E, D, N) = (32, 2048, 512, 512, 2)
#define L_SZ 2048
#define E_SZ 512
#define D_SZ 512
#define ND   1024
// ws layout: dec_proj (32*512 f32) | Bt (512*512 bf16, [n][k]) | scores (32*2048 f32)
#define WS_DEC_OFF 0
#define WS_BT_OFF  (32*512*4)
#define WS_SC_OFF  (32*512*4 + 512*512*2)

typedef unsigned short ushort_t;
typedef unsigned int   uint_t;
typedef __attribute__((ext_vector_type(8))) short short8;   // 8 bf16 (MFMA A/B frag)
typedef __attribute__((ext_vector_type(4))) float floatx4;  // MFMA C/D frag

__device__ __forceinline__ ushort_t f2bf(float f) {
  uint_t u = __builtin_bit_cast(uint_t, f);
  u += 0x7fffu + ((u >> 16) & 1u);
  return (ushort_t)(u >> 16);
}

__device__ __forceinline__ float fast_tanh(float x) {
  float e = __expf(2.0f * x);
  return 1.0f - 2.0f * __builtin_amdgcn_rcpf(e + 1.0f);
}

// async 16B global->LDS DMA; lptr must be wave-uniform, HW deposits lane i at lptr + 16*i
__device__ __forceinline__ void dma16(const ushort_t* g, ushort_t* l) {
  __builtin_amdgcn_global_load_lds(
      (const __attribute__((address_space(1))) uint_t*)(const void*)g,
      (__attribute__((address_space(3))) uint_t*)(void*)l,
      16, 0, 0);
}

// ---------------------------------------------------------------------------
// Prep, 512 blocks:
//  blocks 0..255  : dec_proj[b][d] (b=blk>>3, d-tile=blk&7), k split 4-way + LDS reduce
//  blocks 256..511: Bt[n][k] = bf16(W1[1024+k][n]) via 32x32 LDS transpose tiles
// ---------------------------------------------------------------------------
__global__ __launch_bounds__(256) void prep_k(const float* __restrict__ dh,
                                              const float* __restrict__ W1,
                                              const float* __restrict__ b1,
                                              float* __restrict__ dec,
                                              ushort_t* __restrict__ Bt) {
  int blk = blockIdx.x, t = threadIdx.x;
  if (blk < 256) {
    int b = blk >> 3, d = (blk & 7) * 64 + (t & 63);
    int q = t >> 6;
    __shared__ float red[4][64];
    const float* dfb = dh + b * ND;
    float s = 0.f;
    #pragma unroll 8
    for (int k = q * 256; k < q * 256 + 256; k++)
      s = fmaf(dfb[k], W1[k * D_SZ + d], s);
    red[q][t & 63] = s;
    __syncthreads();
    if (q == 0)
      dec[b * D_SZ + d] = red[0][t] + red[1][t] + red[2][t] + red[3][t] + b1[d];
  } else {
    int tid = blk - 256;
    int tk = (tid >> 4) * 32, tn = (tid & 15) * 32;
    __shared__ float tile[32][33];
    int cc = t & 31, r8 = t >> 5;
    #pragma unroll
    for (int p = 0; p < 4; p++) {
      int r = r8 + p * 8;
      tile[r][cc] = W1[(ND + tk + r) * D_SZ + tn + cc];
    }
    __syncthreads();
    #pragma unroll
    for (int p = 0; p < 4; p++) {
      int nn = r8 + p * 8;
      Bt[(tn + nn) * E_SZ + tk + cc] = f2bf(tile[cc][nn]);
    }
  }
}

// ---------------------------------------------------------------------------
// Main: WG = 512 threads (8 waves) = 64 rows (one b,l-tile) x ALL 512 cols.
// K = 512 in 8 windows of BK=64. A (enc) read from HBM exactly once.
// Wave w owns cols [w*64, w*64+64): 4 mt x 4 nt tiles of 16x16x32, acc[4][4]=64 regs.
// B staged via global_load_lds (async DMA): lane's SOURCE chunk is XOR-permuted so
// the linear DMA deposit (base+16*lane) lands in the swizzled layout
// (row n, pos = c ^ (n&7)) -> conflict-free ds_read_b128 frags.
// A staged via register round-trip (1 chunk = 8 floats/thread), software-pipelined
// one window ahead (issued after the staging barrier -> latency hides under MFMA).
// LDS = 8 + 64 + 0.25 KB = 72.3 KB -> 2 WGs/CU; regs < 128 -> 16 waves/CU.
// ---------------------------------------------------------------------------
__global__ __launch_bounds__(512, 4) void main_k(const float* __restrict__ enc,
                                                 const ushort_t* __restrict__ Bt,
                                                 const float* __restrict__ dec,
                                                 const float* __restrict__ w2,
                                                 float* __restrict__ scores) {
  const int b  = blockIdx.y;
  const int l0 = blockIdx.x * 64;
  const int t  = threadIdx.x;            // 0..511
  const int wave = t >> 6, lane = t & 63;
  const int col = lane & 15, quad = lane >> 4;

  __shared__ ushort_t As[64 * 64];       // 8 KB
  __shared__ ushort_t Bs[512 * 64];      // 64 KB
  __shared__ float s_sc[64];

  if (t < 64) s_sc[t] = 0.f;

  floatx4 acc[4][4];
  #pragma unroll
  for (int mt = 0; mt < 4; mt++)
    #pragma unroll
    for (int nt = 0; nt < 4; nt++)
      acc[mt][nt] = (floatx4){0.f, 0.f, 0.f, 0.f};

  const float* arow = enc + (size_t)(b * L_SZ + l0) * E_SZ;

  // A: thread t owns chunk t: row am, chunk ac (8 floats -> 8 bf16 = 16B)
  const int am = t >> 3, ac = t & 7;
  const float* aptr = arow + am * E_SZ + ac * 8;
  ushort_t* awr = &As[am * 64 + ((ac ^ (am & 7)) << 3)];

  // B DMA source mapping: slot s = wave*512 + j*64 + lane; n = s>>3; c = (s&7)^(n&7)
  const int bn0 = wave * 64 + (lane >> 3);            // row for j=0
  const int bc0 = (lane & 7) ^ ((lane >> 3) & 7);     // chunk, constant over j
  const ushort_t* bptr0 = Bt + bn0 * E_SZ + bc0 * 8;

  float4 pa = *(const float4*)aptr;
  float4 pb = *(const float4*)(aptr + 4);

  #pragma unroll 1
  for (int kw = 0; kw < 8; kw++) {
    __syncthreads();   // previous window's LDS readers done
    // ---- A: cvt prefetched regs -> LDS ----
    union { short8 v; __hip_bfloat162 h[4]; } pk;
    pk.h[0] = __float22bfloat162_rn(make_float2(pa.x, pa.y));
    pk.h[1] = __float22bfloat162_rn(make_float2(pa.z, pa.w));
    pk.h[2] = __float22bfloat162_rn(make_float2(pb.x, pb.y));
    pk.h[3] = __float22bfloat162_rn(make_float2(pb.z, pb.w));
    *(short8*)awr = pk.v;
    // ---- B: 8 async DMAs (64B-row strides of 8 n-rows each) ----
    const ushort_t* bp = bptr0 + kw * 64;
    #pragma unroll
    for (int j = 0; j < 8; j++)
      dma16(bp + j * 8 * E_SZ, &Bs[(wave * 512 + j * 64) * 8]);
    __syncthreads();   // drains DMA (vmcnt) + ds_write (lgkmcnt)
    // ---- prefetch A for next window (latency hides under MFMA below) ----
    if (kw < 7) {
      const float* ap = aptr + (kw + 1) * 64;
      pa = *(const float4*)ap;
      pb = *(const float4*)(ap + 4);
    }
    // ---- MFMA: 2 k-steps of 32 ----
    #pragma unroll
    for (int ks = 0; ks < 2; ks++) {
      short8 af[4], bfr[4];
      #pragma unroll
      for (int mt = 0; mt < 4; mt++) {
        int m = mt * 16 + col;
        af[mt] = *(const short8*)&As[m * 64 + ((((ks << 2) + quad) ^ (m & 7)) << 3)];
      }
      #pragma unroll
      for (int nt = 0; nt < 4; nt++) {
        int n = wave * 64 + nt * 16 + col;
        bfr[nt] = *(const short8*)&Bs[n * 64 + ((((ks << 2) + quad) ^ (n & 7)) << 3)];
      }
      #pragma unroll
      for (int mt = 0; mt < 4; mt++)
        #pragma unroll
        for (int nt = 0; nt < 4; nt++)
          acc[mt][nt] = __builtin_amdgcn_mfma_f32_16x16x32_bf16(af[mt], bfr[nt], acc[mt][nt], 0, 0, 0);
    }
  }

  // ---- epilogue: tanh(acc + dec) . w2, reduced over n ----
  // C/D: D[row=quad*4+r][col] => m = mt*16+quad*4+r, n = wave*64+nt*16+col
  const float* decb = dec + b * D_SZ;
  float sums[4][4];
  #pragma unroll
  for (int mt = 0; mt < 4; mt++)
    #pragma unroll
    for (int r = 0; r < 4; r++) sums[mt][r] = 0.f;

  #pragma unroll
  for (int nt = 0; nt < 4; nt++) {
    int n = wave * 64 + nt * 16 + col;
    float dv = decb[n];
    float wv = w2[n];
    #pragma unroll
    for (int mt = 0; mt < 4; mt++)
      #pragma unroll
      for (int r = 0; r < 4; r++)
        sums[mt][r] += fast_tanh(acc[mt][nt][r] + dv) * wv;
  }
  #pragma unroll
  for (int mt = 0; mt < 4; mt++) {
    #pragma unroll
    for (int r = 0; r < 4; r++) {
      float v = sums[mt][r];
      v += __shfl_xor(v, 1, 16);
      v += __shfl_xor(v, 2, 16);
      v += __shfl_xor(v, 4, 16);
      v += __shfl_xor(v, 8, 16);
      if (col == 0) atomicAdd(&s_sc[mt * 16 + quad * 4 + r], v);  // 8 waves/row
    }
  }
  __syncthreads();
  if (t < 64) scores[b * L_SZ + l0 + t] = s_sc[t];
}

// ---------------------------------------------------------------------------
// Softmax: one WG (1024 threads) per batch row of 2048.
// ---------------------------------------------------------------------------
__global__ __launch_bounds__(1024) void softmax_k(const float* __restrict__ sc,
                                                  float* __restrict__ out) {
  int b = blockIdx.x, t = threadIdx.x;
  int wave = t >> 6, lane = t & 63;
  __shared__ float redm[16], reds[16];
  const float* row = sc + b * L_SZ;
  float v0 = row[t], v1 = row[t + 1024];
  float mx = fmaxf(v0, v1);
  #pragma unroll
  for (int off = 32; off >= 1; off >>= 1) mx = fmaxf(mx, __shfl_xor(mx, off, 64));
  if (lane == 0) redm[wave] = mx;
  __syncthreads();
  float m = redm[0];
  #pragma unroll
  for (int i = 1; i < 16; i++) m = fmaxf(m, redm[i]);
  v0 = __expf(v0 - m);
  v1 = __expf(v1 - m);
  float s = v0 + v1;
  #pragma unroll
  for (int off = 32; off >= 1; off >>= 1) s += __shfl_xor(s, off, 64);
  if (lane == 0) reds[wave] = s;
  __syncthreads();
  float sum = reds[0];
  #pragma unroll
  for (int i = 1; i < 16; i++) sum += reds[i];
  float inv = 1.0f / sum;
  out[b * L_SZ + t]        = v0 * inv;
  out[b * L_SZ + t + 1024] = v1 * inv;
}

extern "C" void kernel_launch(void* const* d_in, const int* in_sizes, int n_in,
                              void* d_out, int out_size, void* d_ws, size_t ws_size,
                              hipStream_t stream) {
  const float* d_hidden = (const float*)d_in[0];   // (32, 2, 512)
  const float* enc      = (const float*)d_in[1];   // (32, 2048, 512)
  const float* W1       = (const float*)d_in[2];   // (1536, 512)
  const float* b1       = (const float*)d_in[3];   // (512,)
  const float* w2       = (const float*)d_in[4];   // (512,)
  float* out = (float*)d_out;                      // (32, 2048)

  char* ws = (char*)d_ws;
  float*    dec = (float*)(ws + WS_DEC_OFF);
  ushort_t* Bt  = (ushort_t*)(ws + WS_BT_OFF);
  float*    sc  = (float*)(ws + WS_SC_OFF);

  prep_k<<<512, 256, 0, stream>>>(d_hidden, W1, b1, dec, Bt);
  main_k<<<dim3(32, 32), 512, 0, stream>>>(enc, Bt, dec, w2, sc);
  softmax_k<<<32, 1024, 0, stream>>>(sc, out);
}